// Round 3
// baseline (509.286 us; speedup 1.0000x reference)
//
#include <hip/hip_runtime.h>

#define NQ 1764
#define NQP 1792             // keys padded to 28*64 (zero-filled in prep)
#define DIM 256
#define KT 64
#define NTILES 28

// ---- attention kernel LDS map (halfword units) ----
#define RM_OFF 0                        // [64 keys][256 d] bf16, xor-swizzled
#define TR_OFF (64 * 256)               // [256 d][64 keys] bf16, xor-swizzled
#define P_OFF  (TR_OFF + 256 * 64)      // 8 waves x [16 q][P_STRIDE]
#define P_STRIDE 40
#define SM_TOTAL (P_OFF + 8 * 16 * P_STRIDE)   // 37888 hw = 75776 B -> 2 blocks/CU

// ---- workspace map (ushort units) ----
#define WS_Q_OFF 0
#define WS_Q_SZ  (16 * NQ * DIM)               // 7,225,344
#define WS_MRM_OFF (WS_Q_OFF + WS_Q_SZ)
#define WS_MRM_SZ (16 * NQP * DIM)             // 7,340,032
#define WS_MTR_OFF (WS_MRM_OFF + WS_MRM_SZ)
#define WS_MTR_SZ (16 * DIM * NQP)
#define WS_NEED_BYTES ((size_t)(WS_MTR_OFF + WS_MTR_SZ) * 2)   // ~43.8 MB

typedef __attribute__((ext_vector_type(4))) short short4v;
typedef __attribute__((ext_vector_type(8))) short short8v;
typedef __attribute__((ext_vector_type(4))) float float4v;

static __device__ __forceinline__ ushort f2bf(float f) {
  union { float f; unsigned u; } v; v.f = f;
  return (ushort)((v.u + 0x7FFFu + ((v.u >> 16) & 1u)) >> 16);  // RNE
}

// ============================ prep kernels ============================

// q = bf16(x * dot_scale), [16][1764][256]
__global__ __launch_bounds__(256)
void prep_q(const float* __restrict__ x, const float* __restrict__ scale,
            ushort* __restrict__ qb)
{
  const int id  = blockIdx.x * 256 + threadIdx.x;   // 903168 total
  const int c8  = (id & 31) * 8;
  const int row = id >> 5;
  const float4v x0 = *(const float4v*)(x + (size_t)row * DIM + c8);
  const float4v x1 = *(const float4v*)(x + (size_t)row * DIM + c8 + 4);
  const float4v s0 = *(const float4v*)(scale + c8);
  const float4v s1 = *(const float4v*)(scale + c8 + 4);
  union { short8v v; short e[8]; } u;
  #pragma unroll
  for (int j = 0; j < 4; ++j) {
    u.e[j]     = (short)f2bf(x0[j] * s0[j]);
    u.e[j + 4] = (short)f2bf(x1[j] * s1[j]);
  }
  *(short8v*)(qb + (size_t)row * DIM + c8) = u.v;
}

// m -> bf16 row-major [16][1792][256] and transposed [16][256][1792]
__global__ __launch_bounds__(256)
void prep_m(const float* __restrict__ mg, ushort* __restrict__ mrm,
            ushort* __restrict__ mtr)
{
  __shared__ float smf[64 * 260];
  const int tid = threadIdx.x;
  const int b   = blockIdx.x & 15;
  const int kt  = blockIdx.x >> 4;
  const int k0  = kt * KT;
  const float* mb = mg + (size_t)b * NQ * DIM;

  #pragma unroll
  for (int i = 0; i < 16; ++i) {
    const int idx = i * 256 + tid;
    const int row = idx >> 6;
    const int c4  = (idx & 63) * 4;
    const int gk  = k0 + row;
    float4v v = (gk < NQ) ? *(const float4v*)(mb + (size_t)gk * DIM + c4)
                          : (float4v){0.f, 0.f, 0.f, 0.f};
    *(float4v*)&smf[row * 260 + c4] = v;
    union { short4v v4; short e[4]; } h;
    #pragma unroll
    for (int j = 0; j < 4; ++j) h.e[j] = (short)f2bf(v[j]);
    *(short4v*)(mrm + ((size_t)b * NQP + k0 + row) * DIM + c4) = h.v4;
  }
  __syncthreads();

  const int d = tid;                         // 0..255
  ushort* dst = mtr + ((size_t)b * DIM + d) * NQP + k0;
  #pragma unroll
  for (int kc = 0; kc < 8; ++kc) {
    union { short8v v; short e[8]; } u;
    #pragma unroll
    for (int j = 0; j < 8; ++j)
      u.e[j] = (short)f2bf(smf[(kc * 8 + j) * 260 + d]);
    *(short8v*)(dst + kc * 8) = u.v;
  }
}

// ============================ attention ============================
// Block = 8 waves. Wave w: queries qblk*64+(w&3)*16, key half (w>>2) of each
// shared 64-key tile; partials combined through LDS. No max-subtract needed
// (|s| small); w_lin additive term cancels in softmax.
__global__ __launch_bounds__(512, 4)
void attn_fused(const ushort* __restrict__ qb, const ushort* __restrict__ mrm,
                const ushort* __restrict__ mtr, const int* __restrict__ maskg,
                const float* __restrict__ x, float* __restrict__ out)
{
  __shared__ ushort sm[SM_TOTAL];
  const int tid  = threadIdx.x;
  const int w    = tid >> 6;
  const int lane = tid & 63;
  const int l15  = lane & 15;
  const int quad = lane >> 4;
  const int l7   = l15 & 7;
  const int kh   = w >> 2;
  const int wq   = w & 3;

  const int b     = blockIdx.x & 15;
  const int qblk  = blockIdx.x >> 4;
  const int qbase = qblk * 64 + wq * 16;

  const ushort* qbb = qb  + (size_t)b * NQ * DIM;
  const ushort* mrb = mrm + (size_t)b * NQP * DIM;
  const ushort* mtb = mtr + (size_t)b * DIM * NQP;
  const int*    mkb = maskg + (size_t)b * NQ;
  const float*  xb  = x + (size_t)b * NQ * DIM;
  float*        ob  = out + (size_t)b * NQ * (2 * DIM);

  // resident Q fragments (already scaled + bf16 in prep)
  short8v qa[8];
  {
    int q = qbase + l15; q = q < NQ ? q : NQ - 1;
    const ushort* qr = qbb + (size_t)q * DIM;
    #pragma unroll
    for (int kk = 0; kk < 8; ++kk)
      qa[kk] = *(const short8v*)(qr + kk * 32 + quad * 8);
  }

  float4v o[16];
  #pragma unroll
  for (int dt = 0; dt < 16; ++dt) o[dt] = (float4v){0.f, 0.f, 0.f, 0.f};
  float l_part[4] = {0.f, 0.f, 0.f, 0.f};

  #pragma unroll 1
  for (int kt = 0; kt < NTILES; ++kt) {
    const int k0 = kt * KT;
    __syncthreads();

    // ---- stage row-major tile, swizzled chunk c' = c ^ (k&7) ----
    #pragma unroll
    for (int j = 0; j < 4; ++j) {
      const int chunk = (w * 4 + j) * 64 + lane;   // 0..2047
      const int k  = chunk >> 5;
      const int cs = chunk & 31;
      const int c  = cs ^ (k & 7);
      const short8v v = *(const short8v*)(mrb + (size_t)(k0 + k) * DIM + c * 8);
      *(short8v*)&sm[RM_OFF + k * 256 + cs * 8] = v;
    }
    // ---- stage transposed tile, swizzled chunk kc' = kc ^ (d&7) ----
    #pragma unroll
    for (int j = 0; j < 4; ++j) {
      const int chunk = (w * 4 + j) * 64 + lane;
      const int d   = chunk >> 3;
      const int ks2 = chunk & 7;
      const int kc  = ks2 ^ (d & 7);
      const short8v v = *(const short8v*)(mtb + (size_t)d * NQP + k0 + kc * 8);
      *(short8v*)&sm[TR_OFF + d * 64 + ks2 * 8] = v;
    }
    __syncthreads();

    bool mv[2];
    #pragma unroll
    for (int ks = 0; ks < 2; ++ks) {
      const int kk2 = k0 + kh * 32 + ks * 16 + l15;
      mv[ks] = (kk2 < NQ) && (mkb[kk2] != 0);
    }

    // ---- S = Q·m^T, p = mask ? exp(s) : 0, P to wave-private LDS ----
    #pragma unroll
    for (int ks = 0; ks < 2; ++ks) {
      const int kloc = kh * 32 + ks * 16 + l15;
      float4v s = (float4v){0.f, 0.f, 0.f, 0.f};
      #pragma unroll
      for (int kk = 0; kk < 8; ++kk) {
        const short8v bv = *(const short8v*)
            &sm[RM_OFF + kloc * 256 + (((kk * 4 + quad) ^ l7) * 8)];
        s = __builtin_amdgcn_mfma_f32_16x16x32_bf16(qa[kk], bv, s, 0, 0, 0);
      }
      #pragma unroll
      for (int r = 0; r < 4; ++r) {
        const float p = mv[ks] ? exp2f(s[r] * 1.44269504089f) : 0.0f;
        l_part[r] += p;
        sm[P_OFF + (w * 16 + quad * 4 + r) * P_STRIDE + ks * 16 + l15] = f2bf(p);
      }
    }

    // ---- O += P·m ----
    {
      const short8v pa = *(const short8v*)
          &sm[P_OFF + (w * 16 + l15) * P_STRIDE + quad * 8];
      #pragma unroll
      for (int dt = 0; dt < 16; ++dt) {
        const int d = dt * 16 + l15;
        const short8v bv = *(const short8v*)
            &sm[TR_OFF + d * 64 + (((kh * 4 + quad) ^ l7) * 8)];
        o[dt] = __builtin_amdgcn_mfma_f32_16x16x32_bf16(pa, bv, o[dt], 0, 0, 0);
      }
    }
  }

  // ---- reduce l over the 16 lanes of each quad ----
  float lsum[4];
  #pragma unroll
  for (int r = 0; r < 4; ++r) {
    float l = l_part[r];
    l += __shfl_xor(l, 1);
    l += __shfl_xor(l, 2);
    l += __shfl_xor(l, 4);
    l += __shfl_xor(l, 8);
    lsum[r] = l;
  }

  // ---- combine key-half partials through LDS ----
  __syncthreads();
  float* fo = (float*)sm;                // [4][16][260]
  float* fl = fo + 4 * 16 * 260;
  if (w >= 4) {
    const int wi = w - 4;
    #pragma unroll
    for (int dt = 0; dt < 16; ++dt)
      #pragma unroll
      for (int r = 0; r < 4; ++r)
        fo[(wi * 16 + quad * 4 + r) * 260 + dt * 16 + l15] = o[dt][r];
    if (l15 == 0)
      #pragma unroll
      for (int r = 0; r < 4; ++r)
        fl[wi * 16 + quad * 4 + r] = lsum[r];
  }
  __syncthreads();
  if (w < 4) {
    #pragma unroll
    for (int r = 0; r < 4; ++r) {
      const int q = qbase + quad * 4 + r;
      const float inv = 1.0f / (lsum[r] + fl[w * 16 + quad * 4 + r]);
      if (q < NQ) {
        float* orow = ob + (size_t)q * (2 * DIM) + DIM + l15;
        #pragma unroll
        for (int dt = 0; dt < 16; ++dt)
          orow[dt * 16] = (o[dt][r] + fo[(w * 16 + quad * 4 + r) * 260 + dt * 16 + l15]) * inv;
      }
    }
  }

  // ---- copy x into first half of concat ----
  #pragma unroll
  for (int i = 0; i < 8; ++i) {
    const int q = qblk * 64 + i * 8 + w;
    if (q < NQ) {
      const float4v v = *(const float4v*)(xb + (size_t)q * DIM + lane * 4);
      *(float4v*)(ob + (size_t)q * (2 * DIM) + lane * 4) = v;
    }
  }
}

// ============== fallback (R1 kernel) if ws is too small ==============
#define F_RM_STRIDE 264
#define F_TR_STRIDE 72
#define F_P_STRIDE 32
#define F_RM_OFF 0
#define F_TR_OFF (64 * F_RM_STRIDE)
#define F_P_OFF (F_TR_OFF + DIM * F_TR_STRIDE)
#define F_SM_TOTAL (F_P_OFF + 8 * 16 * F_P_STRIDE)

__global__ __launch_bounds__(512, 4)
void attn_fallback(const float* __restrict__ x, const float* __restrict__ mg,
                   const int* __restrict__ maskg, const float* __restrict__ scale,
                   float* __restrict__ out)
{
  __shared__ ushort sm[F_SM_TOTAL];
  const int tid = threadIdx.x, w = tid >> 6, lane = tid & 63;
  const int l15 = lane & 15, quad = lane >> 4, kh = w >> 2, wq = w & 3;
  const int b = blockIdx.x & 15, qblk = blockIdx.x >> 4;
  const int qbase = qblk * 64 + wq * 16;
  const float* xb = x + (size_t)b * NQ * DIM;
  const float* mb = mg + (size_t)b * NQ * DIM;
  const int* mkb = maskg + (size_t)b * NQ;
  float* ob = out + (size_t)b * NQ * (2 * DIM);
  short8v qa[8];
  {
    int q = qbase + l15; q = q < NQ ? q : NQ - 1;
    const float* xr = xb + (size_t)q * DIM;
    #pragma unroll
    for (int kk = 0; kk < 8; ++kk) {
      const int dof = kk * 32 + quad * 8;
      const float4v s0 = *(const float4v*)(scale + dof);
      const float4v s1 = *(const float4v*)(scale + dof + 4);
      const float4v x0 = *(const float4v*)(xr + dof);
      const float4v x1 = *(const float4v*)(xr + dof + 4);
      union { short8v v; short e[8]; } u;
      #pragma unroll
      for (int j = 0; j < 4; ++j) {
        u.e[j] = (short)f2bf(x0[j] * s0[j]);
        u.e[j + 4] = (short)f2bf(x1[j] * s1[j]);
      }
      qa[kk] = u.v;
    }
  }
  float4v o[16];
  #pragma unroll
  for (int dt = 0; dt < 16; ++dt) o[dt] = (float4v){0.f, 0.f, 0.f, 0.f};
  float l_part[4] = {0.f, 0.f, 0.f, 0.f};
  #pragma unroll 1
  for (int kt = 0; kt < NTILES; ++kt) {
    const int k0 = kt * KT;
    __syncthreads();
    #pragma unroll
    for (int i = 0; i < 8; ++i) {
      const int row = i * 8 + w;
      int gr = k0 + row; gr = gr < NQ ? gr : NQ - 1;
      const float4v v = *(const float4v*)(mb + (size_t)gr * DIM + lane * 4);
      union { short4v v4; short e[4]; } h;
      #pragma unroll
      for (int j = 0; j < 4; ++j) h.e[j] = (short)f2bf(v[j]);
      *(short4v*)&sm[F_RM_OFF + row * F_RM_STRIDE + lane * 4] = h.v4;
    }
    #pragma unroll
    for (int i = 0; i < 4; ++i) {
      const int r0 = w * 8 + i * 2;
      int g0 = k0 + r0; g0 = g0 < NQ ? g0 : NQ - 1;
      int g1 = k0 + r0 + 1; g1 = g1 < NQ ? g1 : NQ - 1;
      #pragma unroll
      for (int dd = 0; dd < 4; ++dd) {
        const int d = dd * 64 + lane;
        const unsigned pk = (unsigned)f2bf(mb[(size_t)g0 * DIM + d]) |
                            ((unsigned)f2bf(mb[(size_t)g1 * DIM + d]) << 16);
        *(unsigned*)&sm[F_TR_OFF + d * F_TR_STRIDE + r0] = pk;
      }
    }
    __syncthreads();
    bool mv[2];
    #pragma unroll
    for (int ks = 0; ks < 2; ++ks) {
      const int kk2 = k0 + kh * 32 + ks * 16 + l15;
      mv[ks] = (kk2 < NQ) && (mkb[kk2] != 0);
    }
    #pragma unroll
    for (int ks = 0; ks < 2; ++ks) {
      float4v s = (float4v){0.f, 0.f, 0.f, 0.f};
      #pragma unroll
      for (int kk = 0; kk < 8; ++kk) {
        const ushort* bp = &sm[F_RM_OFF + (kh * 32 + ks * 16 + l15) * F_RM_STRIDE + kk * 32 + quad * 8];
        union { short8v v8; short4v v4[2]; } ub;
        ub.v4[0] = *(const short4v*)bp; ub.v4[1] = *(const short4v*)(bp + 4);
        s = __builtin_amdgcn_mfma_f32_16x16x32_bf16(qa[kk], ub.v8, s, 0, 0, 0);
      }
      #pragma unroll
      for (int r = 0; r < 4; ++r) {
        const float p = mv[ks] ? exp2f(s[r] * 1.44269504089f) : 0.0f;
        l_part[r] += p;
        sm[F_P_OFF + (w * 16 + quad * 4 + r) * F_P_STRIDE + ks * 16 + l15] = f2bf(p);
      }
    }
    {
      const short8v pa = *(const short8v*)&sm[F_P_OFF + (w * 16 + l15) * F_P_STRIDE + quad * 8];
      #pragma unroll
      for (int dt = 0; dt < 16; ++dt) {
        const ushort* bp = &sm[F_TR_OFF + (dt * 16 + l15) * F_TR_STRIDE + kh * 32 + quad * 8];
        union { short8v v8; short4v v4[2]; } ub;
        ub.v4[0] = *(const short4v*)bp; ub.v4[1] = *(const short4v*)(bp + 4);
        o[dt] = __builtin_amdgcn_mfma_f32_16x16x32_bf16(pa, ub.v8, o[dt], 0, 0, 0);
      }
    }
  }
  float lsum[4];
  #pragma unroll
  for (int r = 0; r < 4; ++r) {
    float l = l_part[r];
    l += __shfl_xor(l, 1); l += __shfl_xor(l, 2);
    l += __shfl_xor(l, 4); l += __shfl_xor(l, 8);
    lsum[r] = l;
  }
  __syncthreads();
  float* fo = (float*)sm;
  float* fl = fo + 4 * 16 * 260;
  if (w >= 4) {
    const int wi = w - 4;
    #pragma unroll
    for (int dt = 0; dt < 16; ++dt)
      #pragma unroll
      for (int r = 0; r < 4; ++r)
        fo[(wi * 16 + quad * 4 + r) * 260 + dt * 16 + l15] = o[dt][r];
    if (l15 == 0)
      #pragma unroll
      for (int r = 0; r < 4; ++r) fl[wi * 16 + quad * 4 + r] = lsum[r];
  }
  __syncthreads();
  if (w < 4) {
    #pragma unroll
    for (int r = 0; r < 4; ++r) {
      const int q = qbase + quad * 4 + r;
      const float inv = 1.0f / (lsum[r] + fl[w * 16 + quad * 4 + r]);
      if (q < NQ) {
        float* orow = ob + (size_t)q * (2 * DIM) + DIM + l15;
        #pragma unroll
        for (int dt = 0; dt < 16; ++dt)
          orow[dt * 16] = (o[dt][r] + fo[(w * 16 + quad * 4 + r) * 260 + dt * 16 + l15]) * inv;
      }
    }
  }
  #pragma unroll
  for (int i = 0; i < 8; ++i) {
    const int q = qblk * 64 + i * 8 + w;
    if (q < NQ) {
      const float4v v = *(const float4v*)(xb + (size_t)q * DIM + lane * 4);
      *(float4v*)(ob + (size_t)q * (2 * DIM) + lane * 4) = v;
    }
  }
}

extern "C" void kernel_launch(void* const* d_in, const int* in_sizes, int n_in,
                              void* d_out, int out_size, void* d_ws, size_t ws_size,
                              hipStream_t stream) {
  const float* x     = (const float*)d_in[0];
  const float* mem   = (const float*)d_in[1];
  const int*   mask  = (const int*)d_in[2];
  // d_in[3] = w_lin: cancels in softmax (per-row constant) — unused
  const float* scale = (const float*)d_in[4];
  float* out = (float*)d_out;

  if (ws_size >= WS_NEED_BYTES) {
    ushort* wsq = (ushort*)d_ws + WS_Q_OFF;
    ushort* wsm = (ushort*)d_ws + WS_MRM_OFF;
    ushort* wst = (ushort*)d_ws + WS_MTR_OFF;
    prep_q<<<dim3(3528), dim3(256), 0, stream>>>(x, scale, wsq);
    prep_m<<<dim3(448), dim3(256), 0, stream>>>(mem, wsm, wst);
    attn_fused<<<dim3(448), dim3(512), 0, stream>>>(wsq, wsm, wst, mask, x, out);
  } else {
    attn_fallback<<<dim3(448), dim3(512), 0, stream>>>(x, mem, mask, scale, out);
  }
}

// Round 4
// 278.257 us; speedup vs baseline: 1.8303x; 1.8303x over previous
//
#include <hip/hip_runtime.h>

#define NQ 1764
#define NQP 1792             // keys padded to 28*64, zero-filled by prep
#define DIM 256
#define KT 32                // keys per attn tile
#define NTILES 56
#define QBLK 112             // queries stored per block (16 blocks/batch)

// ---- attn LDS map (halfword units), double-buffered tiles ----
#define RM_SZ (KT * DIM)                  // 8192 hw: [32 keys][256 d]
#define TR_SZ (DIM * KT)                  // 8192 hw: [256 d][32 keys]
#define BUF_SZ (RM_SZ + TR_SZ)            // 16384
#define P_OFF (2 * BUF_SZ)                // 32768
#define P_STRIDE 40
#define SM_TOTAL (P_OFF + 4 * 32 * P_STRIDE)   // 37888 hw = 75776 B (proven size)

// ---- workspace map (ushort units) ----
#define WS_MRM_SZ (16 * NQP * DIM)
#define WS_MTR_SZ (16 * DIM * NQP)

typedef __attribute__((ext_vector_type(4))) short short4v;
typedef __attribute__((ext_vector_type(8))) short short8v;
typedef __attribute__((ext_vector_type(4))) float float4v;

static __device__ __forceinline__ ushort f2bf(float f) {
  union { float f; unsigned u; } v; v.f = f;
  return (ushort)((v.u + 0x7FFFu + ((v.u >> 16) & 1u)) >> 16);  // RNE
}

// async global->LDS DMA, 16 B per lane; LDS dest = wave-uniform base + lane*16
static __device__ __forceinline__ void dma16(const void* g, void* l) {
  __builtin_amdgcn_global_load_lds(
      (__attribute__((address_space(1))) void*)(void*)g,
      (__attribute__((address_space(3))) void*)l, 16, 0, 0);
}

// ============================ prep: m -> bf16 RM + TR ============================
__global__ __launch_bounds__(256)
void prep_m(const float* __restrict__ mg, ushort* __restrict__ mrm,
            ushort* __restrict__ mtr)
{
  __shared__ float smf[64 * 260];
  const int tid = threadIdx.x;
  const int b   = blockIdx.x & 15;
  const int kt  = blockIdx.x >> 4;      // 0..27, 64-key chunks
  const int k0  = kt * 64;
  const float* mb = mg + (size_t)b * NQ * DIM;

  #pragma unroll
  for (int i = 0; i < 16; ++i) {
    const int idx = i * 256 + tid;
    const int row = idx >> 6;
    const int c4  = (idx & 63) * 4;
    const int gk  = k0 + row;
    float4v v = (gk < NQ) ? *(const float4v*)(mb + (size_t)gk * DIM + c4)
                          : (float4v){0.f, 0.f, 0.f, 0.f};
    *(float4v*)&smf[row * 260 + c4] = v;
    union { short4v v4; short e[4]; } h;
    #pragma unroll
    for (int j = 0; j < 4; ++j) h.e[j] = (short)f2bf(v[j]);
    *(short4v*)(mrm + ((size_t)b * NQP + k0 + row) * DIM + c4) = h.v4;
  }
  __syncthreads();

  const int d = tid;
  ushort* dst = mtr + ((size_t)b * DIM + d) * NQP + k0;
  #pragma unroll
  for (int kc = 0; kc < 8; ++kc) {
    union { short8v v; short e[8]; } u;
    #pragma unroll
    for (int j = 0; j < 8; ++j)
      u.e[j] = (short)f2bf(smf[(kc * 8 + j) * 260 + d]);
    *(short8v*)(dst + kc * 8) = u.v;
  }
}

// ============================ attention ============================
// Block = 4 waves = 256 threads, 1 block/CU. Wave w owns 32 queries
// (qblk*112 + w*32, two 16-row MFMA subtiles), streams all 1792 keys in
// 32-key tiles, double-buffered via async global_load_lds.
// w_lin cancels in softmax; no max-subtraction needed (|s| small).

static __device__ __forceinline__ void stage_tile(const ushort* mrb, const ushort* mtb,
                                                  ushort* smb, int k0, int w, int lane)
{
  // RM [k][cs] <- global d-chunk cs^(k&7)  (swizzle in the global address)
  #pragma unroll
  for (int j = 0; j < 4; ++j) {
    const int L  = (w * 4 + j) * 64 + lane;   // 0..1023
    const int k  = L >> 5;
    const int cs = L & 31;
    const int gc = cs ^ (k & 7);
    dma16(mrb + (size_t)(k0 + k) * DIM + gc * 8, smb + (w * 4 + j) * 512);
  }
  // TR [d][t] <- global key-chunk t^(d&3)
  #pragma unroll
  for (int j = 0; j < 4; ++j) {
    const int L = (w * 4 + j) * 64 + lane;
    const int d = L >> 2;
    const int t = L & 3;
    const int kc = t ^ (d & 3);
    dma16(mtb + (size_t)d * NQP + k0 + kc * 8, smb + RM_SZ + (w * 4 + j) * 512);
  }
}

__global__ __launch_bounds__(256, 1)
void attn_fused(const float* __restrict__ x, const ushort* __restrict__ mrm,
                const ushort* __restrict__ mtr, const int* __restrict__ maskg,
                const float* __restrict__ scale, float* __restrict__ out)
{
  __shared__ ushort sm[SM_TOTAL];
  const int tid  = threadIdx.x;
  const int w    = tid >> 6;
  const int lane = tid & 63;
  const int l15  = lane & 15;
  const int quad = lane >> 4;
  const int l7   = l15 & 7;

  const int b      = blockIdx.x & 15;
  const int qblk   = blockIdx.x >> 4;     // 0..15
  const int qbase0 = qblk * QBLK;
  const int qbase  = qbase0 + w * 32;

  const float*  xb  = x + (size_t)b * NQ * DIM;
  const ushort* mrb = mrm + (size_t)b * NQP * DIM;
  const ushort* mtb = mtr + (size_t)b * DIM * NQP;
  const int*    mkb = maskg + (size_t)b * NQ;
  float*        ob  = out + (size_t)b * NQ * (2 * DIM);

  // ---- resident Q fragments: two 16-q subtiles, Q = x*scale, bf16, A-layout ----
  short8v qa0[8], qa1[8];
  {
    int q0 = qbase + l15;      q0 = q0 < NQ ? q0 : NQ - 1;
    int q1 = qbase + 16 + l15; q1 = q1 < NQ ? q1 : NQ - 1;
    const float* xr0 = xb + (size_t)q0 * DIM;
    const float* xr1 = xb + (size_t)q1 * DIM;
    #pragma unroll
    for (int kk = 0; kk < 8; ++kk) {
      const int dof = kk * 32 + quad * 8;
      const float4v sa = *(const float4v*)(scale + dof);
      const float4v sb = *(const float4v*)(scale + dof + 4);
      const float4v a0 = *(const float4v*)(xr0 + dof);
      const float4v a1 = *(const float4v*)(xr0 + dof + 4);
      const float4v b0 = *(const float4v*)(xr1 + dof);
      const float4v b1 = *(const float4v*)(xr1 + dof + 4);
      union { short8v v; short e[8]; } u0, u1;
      #pragma unroll
      for (int j = 0; j < 4; ++j) {
        u0.e[j]     = (short)f2bf(a0[j] * sa[j]);
        u0.e[j + 4] = (short)f2bf(a1[j] * sb[j]);
        u1.e[j]     = (short)f2bf(b0[j] * sa[j]);
        u1.e[j + 4] = (short)f2bf(b1[j] * sb[j]);
      }
      qa0[kk] = u0.v;
      qa1[kk] = u1.v;
    }
  }

  float4v o0[16], o1[16];
  #pragma unroll
  for (int dt = 0; dt < 16; ++dt) {
    o0[dt] = (float4v){0.f, 0.f, 0.f, 0.f};
    o1[dt] = (float4v){0.f, 0.f, 0.f, 0.f};
  }
  float l0[4] = {0.f, 0.f, 0.f, 0.f};
  float l1[4] = {0.f, 0.f, 0.f, 0.f};

  stage_tile(mrb, mtb, sm, 0, w, lane);   // prefetch tile 0 -> buf 0

  #pragma unroll 1
  for (int kt = 0; kt < NTILES; ++kt) {
    __syncthreads();   // drains this wave's DMA (vmcnt 0) + syncs buffer reuse
    if (kt + 1 < NTILES)
      stage_tile(mrb, mtb, sm + ((kt + 1) & 1) * BUF_SZ, (kt + 1) * KT, w, lane);

    const int k0 = kt * KT;
    const ushort* rmp = sm + (kt & 1) * BUF_SZ;
    const ushort* trp = rmp + RM_SZ;

    bool mv[2];
    #pragma unroll
    for (int ks = 0; ks < 2; ++ks) {
      const int key = k0 + ks * 16 + l15;
      mv[ks] = (key < NQ) && (mkb[key < NQ ? key : 0] != 0);
    }

    // ---- S = Q·m^T (B-frag shared by both q-subtiles), p = mask?exp(s):0 ----
    #pragma unroll
    for (int ks = 0; ks < 2; ++ks) {
      float4v s0 = (float4v){0.f, 0.f, 0.f, 0.f};
      float4v s1 = (float4v){0.f, 0.f, 0.f, 0.f};
      const ushort* rowp = rmp + (ks * 16 + l15) * DIM;
      #pragma unroll
      for (int kk = 0; kk < 8; ++kk) {
        const short8v bv = *(const short8v*)(rowp + (((kk * 4 + quad) ^ l7) * 8));
        s0 = __builtin_amdgcn_mfma_f32_16x16x32_bf16(qa0[kk], bv, s0, 0, 0, 0);
        s1 = __builtin_amdgcn_mfma_f32_16x16x32_bf16(qa1[kk], bv, s1, 0, 0, 0);
      }
      #pragma unroll
      for (int r = 0; r < 4; ++r) {
        const float p0 = mv[ks] ? exp2f(s0[r] * 1.44269504089f) : 0.0f;
        const float p1 = mv[ks] ? exp2f(s1[r] * 1.44269504089f) : 0.0f;
        l0[r] += p0;
        l1[r] += p1;
        sm[P_OFF + (w * 32 + quad * 4 + r) * P_STRIDE + ks * 16 + l15] = f2bf(p0);
        sm[P_OFF + (w * 32 + 16 + quad * 4 + r) * P_STRIDE + ks * 16 + l15] = f2bf(p1);
      }
    }

    // ---- O += P·m (B-frag shared by both q-subtiles) ----
    {
      const short8v pa0 = *(const short8v*)&sm[P_OFF + (w * 32 + l15) * P_STRIDE + quad * 8];
      const short8v pa1 = *(const short8v*)&sm[P_OFF + (w * 32 + 16 + l15) * P_STRIDE + quad * 8];
      #pragma unroll
      for (int dt = 0; dt < 16; ++dt) {
        const int d = dt * 16 + l15;
        const short8v bv = *(const short8v*)(trp + d * KT + ((quad ^ (d & 3)) * 8));
        o0[dt] = __builtin_amdgcn_mfma_f32_16x16x32_bf16(pa0, bv, o0[dt], 0, 0, 0);
        o1[dt] = __builtin_amdgcn_mfma_f32_16x16x32_bf16(pa1, bv, o1[dt], 0, 0, 0);
      }
    }
  }

  // ---- reduce l over the 16 lanes of each quad ----
  float il0[4], il1[4];
  #pragma unroll
  for (int r = 0; r < 4; ++r) {
    float a = l0[r], c = l1[r];
    a += __shfl_xor(a, 1); a += __shfl_xor(a, 2);
    a += __shfl_xor(a, 4); a += __shfl_xor(a, 8);
    c += __shfl_xor(c, 1); c += __shfl_xor(c, 2);
    c += __shfl_xor(c, 4); c += __shfl_xor(c, 8);
    il0[r] = 1.0f / a;
    il1[r] = 1.0f / c;
  }

  __syncthreads();   // tiles + P dead; reuse LDS for O transpose
  float* ew = (float*)sm + w * 4160;   // per-wave [16 q][260] fp32
  #pragma unroll
  for (int qs = 0; qs < 2; ++qs) {
    #pragma unroll
    for (int dt = 0; dt < 16; ++dt)
      #pragma unroll
      for (int r = 0; r < 4; ++r)
        ew[(quad * 4 + r) * 260 + dt * 16 + l15] =
            qs ? (o1[dt][r] * il1[r]) : (o0[dt][r] * il0[r]);
    #pragma unroll
    for (int i = 0; i < 4; ++i)
      #pragma unroll
      for (int jj = 0; jj < 4; ++jj) {
        const int row = i * 4 + quad;
        const int lq  = w * 32 + qs * 16 + row;
        const int q   = qbase0 + lq;
        if (lq < QBLK && q < NQ) {
          const float4v v = *(const float4v*)&ew[row * 260 + (jj * 16 + l15) * 4];
          *(float4v*)(ob + (size_t)q * (2 * DIM) + DIM + (jj * 16 + l15) * 4) = v;
        }
      }
  }

  // ---- copy x into first half of concat (block's own 112 queries) ----
  #pragma unroll
  for (int i = 0; i < 28; ++i) {
    const int idx = i * 256 + tid;      // 0..7167
    const int row = idx >> 6;           // 0..111
    const int c4  = (idx & 63) * 4;
    const int q   = qbase0 + row;
    if (q < NQ) {
      const float4v v = *(const float4v*)(xb + (size_t)q * DIM + c4);
      *(float4v*)(ob + (size_t)q * (2 * DIM) + c4) = v;
    }
  }
}

extern "C" void kernel_launch(void* const* d_in, const int* in_sizes, int n_in,
                              void* d_out, int out_size, void* d_ws, size_t ws_size,
                              hipStream_t stream) {
  const float* x     = (const float*)d_in[0];
  const float* mem   = (const float*)d_in[1];
  const int*   mask  = (const int*)d_in[2];
  // d_in[3] = w_lin: cancels in softmax (per-row constant) — unused
  const float* scale = (const float*)d_in[4];
  float* out = (float*)d_out;

  ushort* wsm = (ushort*)d_ws;               // bf16 m, row-major [16][1792][256]
  ushort* wst = wsm + WS_MRM_SZ;             // bf16 m, transposed [16][256][1792]

  prep_m<<<dim3(448), dim3(256), 0, stream>>>(mem, wsm, wst);
  // 16 batches x 16 q-blocks of 112 queries = 256 blocks = 1 per CU
  attn_fused<<<dim3(256), dim3(256), 0, stream>>>(x, wsm, wst, mask, scale, out);
}